// Round 4
// baseline (182.835 us; speedup 1.0000x reference)
//
#include <hip/hip_runtime.h>
#include <stdint.h>

constexpr int B = 4;
constexpr int L = 2048;
constexpr int H = 8;
constexpr int D = 64;
constexpr int S = 40;    // sampled keys per query
constexpr int U = 40;    // top-k queries
constexpr int HD = H * D;          // 512
constexpr int NSEG = 8;            // top-k segments per (b,h)
constexpr int SEGL = L / NSEG;     // 256
constexpr int NC = 64;             // cumsum chunks
constexpr int CL = L / NC;         // 32

constexpr int NBLK_SCORES = B * L / 4;     // 2048
constexpr int NBLK_CHUNK  = B * NC;        // 256
constexpr int NBLK_FLAG   = 64;            // zero 256 KB of flags, 4 KB/block

// monotone float->uint mapping: larger float => larger uint
__device__ __forceinline__ unsigned mono(float v) {
    unsigned u = __float_as_uint(v);
    return (u & 0x80000000u) ? ~u : (u | 0x80000000u);
}

typedef float f4v __attribute__((ext_vector_type(4)));

__device__ __forceinline__ float4 ntload4(const float4* p) {
    f4v v = __builtin_nontemporal_load((const f4v*)p);
    return make_float4(v.x, v.y, v.z, v.w);
}

// ---------------------------------------------------------------------------
// D1: fused sampled-scores + V-chunksum + flags-zero.
//  blocks [0,2048):       M[b,h,q] for all 8 heads, one wave per (b,q)
//                         (XCD swizzle pins each b's K slab to 2 XCDs)
//  blocks [2048,2304):    per-chunk V totals (2 hd per thread)
//  blocks [2304,2368):    zero flags (int4)
// The chunksum HBM stream runs in the shadow of the L2-bound scores gather.
// ---------------------------------------------------------------------------
__global__ __launch_bounds__(256) void k_scores_chunks(
    const float4* __restrict__ Q4, const float4* __restrict__ K4,
    const int* __restrict__ idxs, const float* __restrict__ V,
    float* __restrict__ M, float* __restrict__ partial,
    int* __restrict__ flags)
{
    int i = blockIdx.x;

    if (i < NBLK_SCORES) {
        // ---------------- sampled scores ----------------
        int xcd = i & 7;
        int b = xcd >> 1;
        int qc = (i >> 3) * 2 + (xcd & 1);  // 0..511
        int w = threadIdx.x >> 6;
        int lane = threadIdx.x & 63;
        int q = qc * 4 + w;
        int h = lane >> 3;
        int dd = lane & 7;

        const float4* qrow = Q4 + (size_t)(b * L + q) * 128;
        float4 qa = ntload4(qrow + 2 * lane);
        float4 qb = ntload4(qrow + 2 * lane + 1);

        int v_idx = idxs[q * S + (lane < S ? lane : 0)];

        const float4* kbase = K4 + (size_t)b * L * 128;
        float mx = -INFINITY, sm = 0.f;
        #pragma unroll 8
        for (int s = 0; s < S; ++s) {
            int ki = __shfl(v_idx, s);
            const float4* krow = kbase + (size_t)ki * 128;
            float4 ka = krow[2 * lane], kb = krow[2 * lane + 1];
            float d = qa.x * ka.x + qa.y * ka.y + qa.z * ka.z + qa.w * ka.w
                    + qb.x * kb.x + qb.y * kb.y + qb.z * kb.z + qb.w * kb.w;
            d += __shfl_xor(d, 1);
            d += __shfl_xor(d, 2);
            d += __shfl_xor(d, 4);
            mx = fmaxf(mx, d);
            sm += d;
        }
        if (dd == 0)
            M[(b * 8 + h) * L + q] = mx - sm * (1.0f / (float)L);
    } else if (i < NBLK_SCORES + NBLK_CHUNK) {
        // ---------------- V chunk totals ----------------
        int cidx = i - NBLK_SCORES;
        int b = cidx >> 6, c = cidx & 63;
        int t = threadIdx.x;
        const float* vp = V + ((size_t)(b * L + c * CL)) * HD;
        float s0 = 0.f, s1 = 0.f;
        #pragma unroll
        for (int l = 0; l < CL; ++l) {
            s0 += __builtin_nontemporal_load(vp + (size_t)l * HD + t);
            s1 += __builtin_nontemporal_load(vp + (size_t)l * HD + t + 256);
        }
        partial[((size_t)b * NC + c) * HD + t]       = s0;
        partial[((size_t)b * NC + c) * HD + t + 256] = s1;
    } else {
        // ---------------- zero flags ----------------
        int fidx = i - (NBLK_SCORES + NBLK_CHUNK);   // 0..63
        ((int4*)flags)[fidx * 256 + threadIdx.x] = make_int4(0, 0, 0, 0);
    }
}

// ---------------------------------------------------------------------------
// D2: per-segment exact top-40 by rank counting. 256 one-wave blocks -> the
// ~4.4k-VALU/thread rank-count runs at 1 wave/CU across the whole chip
// instead of 8 waves on 32 CUs.
// ---------------------------------------------------------------------------
__global__ __launch_bounds__(64) void k_seg_topk(
    const float* __restrict__ M, unsigned long long* __restrict__ cand)
{
    int blk = blockIdx.x;           // bh*NSEG + seg
    int bh = blk >> 3, seg = blk & 7;
    int lane = threadIdx.x;
    int j0 = seg * SEGL + lane * 4;

    float4 v = *(const float4*)(M + (size_t)bh * L + j0);
    unsigned m[4] = { mono(v.x), mono(v.y), mono(v.z), mono(v.w) };
    int rank[4] = { 0, 0, 0, 0 };

    #pragma unroll 4
    for (int src = 0; src < 64; ++src) {
        #pragma unroll
        for (int slot = 0; slot < 4; ++slot) {
            unsigned bm = __shfl(m[slot], src);
            int bj = src * 4 + slot;
            #pragma unroll
            for (int s = 0; s < 4; ++s) {
                int myj = lane * 4 + s;
                rank[s] += (bm > m[s]) || (bm == m[s] && bj < myj);
            }
        }
    }

    unsigned long long* out = cand + (size_t)blk * U;
    #pragma unroll
    for (int s = 0; s < 4; ++s)
        if (rank[s] < U)
            out[rank[s]] = ((unsigned long long)m[s] << 32)
                         | (unsigned)(~(unsigned)(j0 + s));
}

// ---------------------------------------------------------------------------
// D3: merge 320->top-40 + 40x40 triangle attention, one block per (b,h).
// All phases lane-parallel with compile-time bounds (in-register softmax
// via shfl_xor butterflies, transposed pad-65 K tile, unrolled PV).
// ---------------------------------------------------------------------------
__global__ __launch_bounds__(512) void k_attn(
    const unsigned long long* __restrict__ cand, const float4* __restrict__ Q4,
    const float4* __restrict__ K4, const float4* __restrict__ V4,
    int* __restrict__ flags, float* __restrict__ upd)
{
    __shared__ unsigned long long cnd[NSEG * U];       // 320 candidates
    __shared__ int top_idx[U];
    __shared__ __align__(16) float Qs[U * 68];         // row-major, pad 68
    __shared__ __align__(16) float Kst[64 * 65];       // TRANSPOSED: [d*65+k]
    __shared__ __align__(16) float Vs[U * 68];         // row-major, pad 68
    __shared__ __align__(16) float Plds[U * 44];       // zero-padded rows

    int bh = blockIdx.x;
    int b = bh >> 3, h = bh & 7;
    int tid = threadIdx.x;
    int wv = tid >> 6, lane = tid & 63;

    for (int t = tid; t < NSEG * U; t += 512)
        cnd[t] = cand[(size_t)bh * NSEG * U + t];
    __syncthreads();

    // ---- merge: top-40 of 320, one candidate/thread, unrolled LDS scan ----
    if (tid < NSEG * U) {
        unsigned long long ka = cnd[tid];
        int ra = 0;
        #pragma unroll 8
        for (int j = 0; j < NSEG * U; ++j) ra += (cnd[j] > ka);
        if (ra < U) top_idx[ra] = (int)(~(unsigned)ka);
    }
    __syncthreads();

    if (tid < U) flags[bh * L + top_idx[tid]] = tid + 1;

    // ---- stage K (transposed), V, Q[top_idx[r]] ---------------------------
    for (int i = tid; i < U * 16; i += 512) {
        int r = i >> 4, d4 = i & 15;
        size_t kvbase = ((size_t)(b * L + r) * H + h) * 16 + d4;
        float4 kv = K4[kvbase];
        Kst[(4 * d4 + 0) * 65 + r] = kv.x;
        Kst[(4 * d4 + 1) * 65 + r] = kv.y;
        Kst[(4 * d4 + 2) * 65 + r] = kv.z;
        Kst[(4 * d4 + 3) * 65 + r] = kv.w;
        *(float4*)(Vs + r * 68 + d4 * 4) = V4[kvbase];
        *(float4*)(Qs + r * 68 + d4 * 4) =
            Q4[((size_t)(b * L + top_idx[r]) * H + h) * 16 + d4];
    }
    __syncthreads();

    // ---- scores + in-register softmax, wave-parallel ----------------------
    // wave wv owns rows 5*wv .. 5*wv+4; lane k = key index (k>=40 masked).
    const float scale = 0.125f;   // 1/sqrt(64)
    int k = lane;
    for (int rr = 0; rr < 5; ++rr) {
        int r = wv * 5 + rr;
        float acc = 0.f;
        #pragma unroll
        for (int d0 = 0; d0 < D; d0 += 4) {
            float4 qv = *(const float4*)(Qs + r * 68 + d0);   // broadcast
            acc += qv.x * Kst[(d0 + 0) * 65 + k];
            acc += qv.y * Kst[(d0 + 1) * 65 + k];
            acc += qv.z * Kst[(d0 + 2) * 65 + k];
            acc += qv.w * Kst[(d0 + 3) * 65 + k];
        }
        // causal over rank: keys k<=r only (k<=r implies k<40)
        float sc = (k <= r) ? acc * scale : -INFINITY;
        float mx = sc;
        #pragma unroll
        for (int off = 32; off >= 1; off >>= 1)
            mx = fmaxf(mx, __shfl_xor(mx, off));
        float e = __expf(sc - mx);            // masked lanes -> 0
        float sum = e;
        #pragma unroll
        for (int off = 32; off >= 1; off >>= 1)
            sum += __shfl_xor(sum, off);
        float p = e / sum;
        if (k < U) Plds[r * 44 + k] = p;      // zeros where masked
    }
    __syncthreads();

    // ---- PV, fixed-40 fully unrolled --------------------------------------
    for (int t = tid; t < U * D; t += 512) {
        int r = t >> 6, d = t & 63;
        float acc = 0.f;
        #pragma unroll
        for (int kk = 0; kk < U; kk += 4) {
            float4 pv = *(const float4*)(Plds + r * 44 + kk);  // broadcast
            acc += pv.x * Vs[(kk + 0) * 68 + d];
            acc += pv.y * Vs[(kk + 1) * 68 + d];
            acc += pv.z * Vs[(kk + 2) * 68 + d];
            acc += pv.w * Vs[(kk + 3) * 68 + d];
        }
        upd[((size_t)bh * U + r) * D + d] = acc;
    }
}

// ---------------------------------------------------------------------------
// D4: emit. Each block (b,c) computes its exclusive prefix by summing the
// c predecessor chunk totals (L2-resident, redundant but deadlock-free),
// then emits cumsum with flagged rows replaced by upd.
// ---------------------------------------------------------------------------
__global__ __launch_bounds__(512) void k_out(
    const float* __restrict__ V, const float* __restrict__ partial,
    const int* __restrict__ flags, const float* __restrict__ upd,
    float* __restrict__ out)
{
    int b = blockIdx.x >> 6;
    int c = blockIdx.x & 63;
    int hd = threadIdx.x;
    int h = hd >> 6, d = hd & 63;

    // exclusive prefix over predecessor chunk totals
    float acc = 0.f;
    const float* pp = partial + (size_t)b * NC * HD + hd;
    for (int j = 0; j < c; ++j) acc += pp[(size_t)j * HD];

    const float* vp = V + ((size_t)(b * L + c * CL)) * HD + hd;
    float*       op = out + ((size_t)(b * L + c * CL)) * HD + hd;
    const int*   fp = flags + (b * H + h) * L + c * CL;
    const float* up = upd + (size_t)(b * H + h) * U * D + d;

    #pragma unroll 4
    for (int l = 0; l < CL; ++l) {
        acc += vp[(size_t)l * HD];
        int f = fp[l];
        float o = f ? up[(size_t)(f - 1) * D] : acc;
        __builtin_nontemporal_store(o, op + (size_t)l * HD);
    }
}

extern "C" void kernel_launch(void* const* d_in, const int* in_sizes, int n_in,
                              void* d_out, int out_size, void* d_ws, size_t ws_size,
                              hipStream_t stream)
{
    const float* Q   = (const float*)d_in[0];
    const float* K   = (const float*)d_in[1];
    const float* V   = (const float*)d_in[2];
    const int*  idxs = (const int*)d_in[3];
    float* out = (float*)d_out;

    char* ws = (char*)d_ws;
    float* M        = (float*)(ws);                 // B*H*L          = 256 KB
    int*   flags    = (int*)  (ws + 262144);        // B*H*L          = 256 KB
    float* upd      = (float*)(ws + 524288);        // B*H*U*D        = 320 KB
    float* partial  = (float*)(ws + 851968);        // B*NC*HD        = 512 KB
    unsigned long long* cand = (unsigned long long*)(ws + 1376256);  // 80 KB

    k_scores_chunks<<<NBLK_SCORES + NBLK_CHUNK + NBLK_FLAG, 256, 0, stream>>>(
        (const float4*)Q, (const float4*)K, idxs, V, M, partial, flags);
    k_seg_topk <<<B * H * NSEG, 64, 0, stream>>>(M, cand);
    k_attn     <<<B * H,       512, 0, stream>>>(cand, (const float4*)Q, (const float4*)K,
                                                 (const float4*)V, flags, upd);
    k_out      <<<B * NC,      512, 0, stream>>>(V, partial, flags, upd, out);
}

// Round 5
// 178.059 us; speedup vs baseline: 1.0268x; 1.0268x over previous
//
#include <hip/hip_runtime.h>
#include <stdint.h>

constexpr int B = 4;
constexpr int L = 2048;
constexpr int H = 8;
constexpr int D = 64;
constexpr int S = 40;    // sampled keys per query
constexpr int U = 40;    // top-k queries
constexpr int HD = H * D;          // 512
constexpr int NSEG = 8;            // top-k segments per (b,h)
constexpr int SEGL = L / NSEG;     // 256
constexpr int NC = 64;             // cumsum chunks
constexpr int CL = L / NC;         // 32
constexpr int ROCT = 8;            // row-octets per (b,h): 5 rows each
constexpr int RPO = U / ROCT;      // 5 rows per octet

constexpr int NBLK_SCORES = B * L / 4;     // 2048
constexpr int NBLK_CHUNK  = B * NC;        // 256
constexpr int NBLK_FLAG   = 64;            // zero 256 KB of flags, 4 KB/block

// monotone float->uint mapping: larger float => larger uint
__device__ __forceinline__ unsigned mono(float v) {
    unsigned u = __float_as_uint(v);
    return (u & 0x80000000u) ? ~u : (u | 0x80000000u);
}

typedef float f4v __attribute__((ext_vector_type(4)));

__device__ __forceinline__ float4 ntload4(const float4* p) {
    f4v v = __builtin_nontemporal_load((const f4v*)p);
    return make_float4(v.x, v.y, v.z, v.w);
}

// ---------------------------------------------------------------------------
// D1: fused sampled-scores + V-chunksum + flags-zero.
//  blocks [0,2048):       M[b,h,q] for all 8 heads, one wave per (b,q)
//                         (XCD swizzle pins each b's K slab to 2 XCDs)
//  blocks [2048,2304):    per-chunk V totals (2 hd per thread)
//  blocks [2304,2368):    zero flags (int4)
// ---------------------------------------------------------------------------
__global__ __launch_bounds__(256) void k_scores_chunks(
    const float4* __restrict__ Q4, const float4* __restrict__ K4,
    const int* __restrict__ idxs, const float* __restrict__ V,
    float* __restrict__ M, float* __restrict__ partial,
    int* __restrict__ flags)
{
    int i = blockIdx.x;

    if (i < NBLK_SCORES) {
        // ---------------- sampled scores ----------------
        int xcd = i & 7;
        int b = xcd >> 1;
        int qc = (i >> 3) * 2 + (xcd & 1);  // 0..511
        int w = threadIdx.x >> 6;
        int lane = threadIdx.x & 63;
        int q = qc * 4 + w;
        int h = lane >> 3;
        int dd = lane & 7;

        const float4* qrow = Q4 + (size_t)(b * L + q) * 128;
        float4 qa = ntload4(qrow + 2 * lane);
        float4 qb = ntload4(qrow + 2 * lane + 1);

        int v_idx = idxs[q * S + (lane < S ? lane : 0)];

        const float4* kbase = K4 + (size_t)b * L * 128;
        float mx = -INFINITY, sm = 0.f;
        #pragma unroll 8
        for (int s = 0; s < S; ++s) {
            int ki = __shfl(v_idx, s);
            const float4* krow = kbase + (size_t)ki * 128;
            float4 ka = krow[2 * lane], kb = krow[2 * lane + 1];
            float d = qa.x * ka.x + qa.y * ka.y + qa.z * ka.z + qa.w * ka.w
                    + qb.x * kb.x + qb.y * kb.y + qb.z * kb.z + qb.w * kb.w;
            d += __shfl_xor(d, 1);
            d += __shfl_xor(d, 2);
            d += __shfl_xor(d, 4);
            mx = fmaxf(mx, d);
            sm += d;
        }
        if (dd == 0)
            M[(b * 8 + h) * L + q] = mx - sm * (1.0f / (float)L);
    } else if (i < NBLK_SCORES + NBLK_CHUNK) {
        // ---------------- V chunk totals ----------------
        int cidx = i - NBLK_SCORES;
        int b = cidx >> 6, c = cidx & 63;
        int t = threadIdx.x;
        const float* vp = V + ((size_t)(b * L + c * CL)) * HD;
        float s0 = 0.f, s1 = 0.f;
        #pragma unroll
        for (int l = 0; l < CL; ++l) {
            s0 += __builtin_nontemporal_load(vp + (size_t)l * HD + t);
            s1 += __builtin_nontemporal_load(vp + (size_t)l * HD + t + 256);
        }
        partial[((size_t)b * NC + c) * HD + t]       = s0;
        partial[((size_t)b * NC + c) * HD + t + 256] = s1;
    } else {
        // ---------------- zero flags ----------------
        int fidx = i - (NBLK_SCORES + NBLK_CHUNK);   // 0..63
        ((int4*)flags)[fidx * 256 + threadIdx.x] = make_int4(0, 0, 0, 0);
    }
}

// ---------------------------------------------------------------------------
// D2: per-segment exact top-40 by rank counting. 256 one-wave blocks.
// ---------------------------------------------------------------------------
__global__ __launch_bounds__(64) void k_seg_topk(
    const float* __restrict__ M, unsigned long long* __restrict__ cand)
{
    int blk = blockIdx.x;           // bh*NSEG + seg
    int bh = blk >> 3, seg = blk & 7;
    int lane = threadIdx.x;
    int j0 = seg * SEGL + lane * 4;

    float4 v = *(const float4*)(M + (size_t)bh * L + j0);
    unsigned m[4] = { mono(v.x), mono(v.y), mono(v.z), mono(v.w) };
    int rank[4] = { 0, 0, 0, 0 };

    #pragma unroll 4
    for (int src = 0; src < 64; ++src) {
        #pragma unroll
        for (int slot = 0; slot < 4; ++slot) {
            unsigned bm = __shfl(m[slot], src);
            int bj = src * 4 + slot;
            #pragma unroll
            for (int s = 0; s < 4; ++s) {
                int myj = lane * 4 + s;
                rank[s] += (bm > m[s]) || (bm == m[s] && bj < myj);
            }
        }
    }

    unsigned long long* out = cand + (size_t)blk * U;
    #pragma unroll
    for (int s = 0; s < 4; ++s)
        if (rank[s] < U)
            out[rank[s]] = ((unsigned long long)m[s] << 32)
                         | (unsigned)(~(unsigned)(j0 + s));
}

// ---------------------------------------------------------------------------
// D3: attention spread 8x: one block per (b,h,row-octet). Each block
// redundantly recomputes the 320->40 merge (unrolled LDS broadcast scan,
// ~2us), stages all 40 K/V rows + its 5 Q rows, runs one row per wave
// (lane = key, in-register shfl softmax), writes its 5 upd rows.
// Only octet 0 writes flags. 256 blocks -> full-chip, no latency
// serialization on a 32-block grid.
// ---------------------------------------------------------------------------
__global__ __launch_bounds__(512) void k_attn(
    const unsigned long long* __restrict__ cand, const float4* __restrict__ Q4,
    const float4* __restrict__ K4, const float4* __restrict__ V4,
    int* __restrict__ flags, float* __restrict__ upd)
{
    __shared__ unsigned long long cnd[NSEG * U];       // 320 candidates
    __shared__ int top_idx[U];
    __shared__ __align__(16) float Qs[RPO * 68];       // 5 rows, pad 68
    __shared__ __align__(16) float Kst[64 * 65];       // TRANSPOSED: [d*65+k]
    __shared__ __align__(16) float Vs[U * 68];         // row-major, pad 68
    __shared__ __align__(16) float Plds[RPO * 44];     // zero-padded rows

    int blk = blockIdx.x;
    int bh = blk >> 3, oct = blk & 7;
    int b = bh >> 3, h = bh & 7;
    int tid = threadIdx.x;
    int wv = tid >> 6, lane = tid & 63;

    for (int t = tid; t < NSEG * U; t += 512)
        cnd[t] = cand[(size_t)bh * NSEG * U + t];
    __syncthreads();

    // ---- merge: top-40 of 320, one candidate/thread, unrolled LDS scan ----
    if (tid < NSEG * U) {
        unsigned long long ka = cnd[tid];
        int ra = 0;
        #pragma unroll 8
        for (int j = 0; j < NSEG * U; ++j) ra += (cnd[j] > ka);
        if (ra < U) top_idx[ra] = (int)(~(unsigned)ka);
    }
    __syncthreads();

    if (oct == 0 && tid < U) flags[bh * L + top_idx[tid]] = tid + 1;

    // ---- stage K rows 0..39 (transposed), V rows 0..39, 5 Q rows ----------
    for (int i = tid; i < U * 16; i += 512) {
        int r = i >> 4, d4 = i & 15;
        size_t kvbase = ((size_t)(b * L + r) * H + h) * 16 + d4;
        float4 kv = K4[kvbase];
        Kst[(4 * d4 + 0) * 65 + r] = kv.x;
        Kst[(4 * d4 + 1) * 65 + r] = kv.y;
        Kst[(4 * d4 + 2) * 65 + r] = kv.z;
        Kst[(4 * d4 + 3) * 65 + r] = kv.w;
        *(float4*)(Vs + r * 68 + d4 * 4) = V4[kvbase];
    }
    if (tid < RPO * 16) {
        int rl = tid >> 4, d4 = tid & 15;
        int qg = top_idx[oct * RPO + rl];
        *(float4*)(Qs + rl * 68 + d4 * 4) =
            Q4[((size_t)(b * L + qg) * H + h) * 16 + d4];
    }
    __syncthreads();

    // ---- scores + in-register softmax: wave wv<5 owns global row ----------
    const float scale = 0.125f;   // 1/sqrt(64)
    if (wv < RPO) {
        int rg = oct * RPO + wv;   // global rank row
        int k = lane;
        float acc = 0.f;
        #pragma unroll
        for (int d0 = 0; d0 < D; d0 += 4) {
            float4 qv = *(const float4*)(Qs + wv * 68 + d0);   // broadcast
            acc += qv.x * Kst[(d0 + 0) * 65 + k];
            acc += qv.y * Kst[(d0 + 1) * 65 + k];
            acc += qv.z * Kst[(d0 + 2) * 65 + k];
            acc += qv.w * Kst[(d0 + 3) * 65 + k];
        }
        // causal over rank: keys k<=rg only
        float sc = (k <= rg) ? acc * scale : -INFINITY;
        float mx = sc;
        #pragma unroll
        for (int off = 32; off >= 1; off >>= 1)
            mx = fmaxf(mx, __shfl_xor(mx, off));
        float e = __expf(sc - mx);            // masked lanes -> 0
        float sum = e;
        #pragma unroll
        for (int off = 32; off >= 1; off >>= 1)
            sum += __shfl_xor(sum, off);
        float p = e / sum;
        if (k < U) Plds[wv * 44 + k] = p;     // zeros where masked
    }
    __syncthreads();

    // ---- PV: 5 rows x 64 dims, fixed-40 fully unrolled --------------------
    if (tid < RPO * D) {
        int rl = tid >> 6, d = tid & 63;
        float acc = 0.f;
        #pragma unroll
        for (int kk = 0; kk < U; kk += 4) {
            float4 pv = *(const float4*)(Plds + rl * 44 + kk);  // broadcast
            acc += pv.x * Vs[(kk + 0) * 68 + d];
            acc += pv.y * Vs[(kk + 1) * 68 + d];
            acc += pv.z * Vs[(kk + 2) * 68 + d];
            acc += pv.w * Vs[(kk + 3) * 68 + d];
        }
        upd[((size_t)bh * U + oct * RPO + rl) * D + d] = acc;
    }
}

// ---------------------------------------------------------------------------
// D4: emit. Each block (b,c) computes its exclusive prefix by summing the
// c predecessor chunk totals (L2-resident, redundant but deadlock-free),
// then emits cumsum with flagged rows replaced by upd.
// ---------------------------------------------------------------------------
__global__ __launch_bounds__(512) void k_out(
    const float* __restrict__ V, const float* __restrict__ partial,
    const int* __restrict__ flags, const float* __restrict__ upd,
    float* __restrict__ out)
{
    int b = blockIdx.x >> 6;
    int c = blockIdx.x & 63;
    int hd = threadIdx.x;
    int h = hd >> 6, d = hd & 63;

    // exclusive prefix over predecessor chunk totals
    float acc = 0.f;
    const float* pp = partial + (size_t)b * NC * HD + hd;
    for (int j = 0; j < c; ++j) acc += pp[(size_t)j * HD];

    const float* vp = V + ((size_t)(b * L + c * CL)) * HD + hd;
    float*       op = out + ((size_t)(b * L + c * CL)) * HD + hd;
    const int*   fp = flags + (b * H + h) * L + c * CL;
    const float* up = upd + (size_t)(b * H + h) * U * D + d;

    #pragma unroll 4
    for (int l = 0; l < CL; ++l) {
        acc += vp[(size_t)l * HD];
        int f = fp[l];
        float o = f ? up[(size_t)(f - 1) * D] : acc;
        __builtin_nontemporal_store(o, op + (size_t)l * HD);
    }
}

extern "C" void kernel_launch(void* const* d_in, const int* in_sizes, int n_in,
                              void* d_out, int out_size, void* d_ws, size_t ws_size,
                              hipStream_t stream)
{
    const float* Q   = (const float*)d_in[0];
    const float* K   = (const float*)d_in[1];
    const float* V   = (const float*)d_in[2];
    const int*  idxs = (const int*)d_in[3];
    float* out = (float*)d_out;

    char* ws = (char*)d_ws;
    float* M        = (float*)(ws);                 // B*H*L          = 256 KB
    int*   flags    = (int*)  (ws + 262144);        // B*H*L          = 256 KB
    float* upd      = (float*)(ws + 524288);        // B*H*U*D        = 320 KB
    float* partial  = (float*)(ws + 851968);        // B*NC*HD        = 512 KB
    unsigned long long* cand = (unsigned long long*)(ws + 1376256);  // 80 KB

    k_scores_chunks<<<NBLK_SCORES + NBLK_CHUNK + NBLK_FLAG, 256, 0, stream>>>(
        (const float4*)Q, (const float4*)K, idxs, V, M, partial, flags);
    k_seg_topk <<<B * H * NSEG, 64, 0, stream>>>(M, cand);
    k_attn     <<<B * H * ROCT, 512, 0, stream>>>(cand, (const float4*)Q, (const float4*)K,
                                                  (const float4*)V, flags, upd);
    k_out      <<<B * NC,      512, 0, stream>>>(V, partial, flags, upd, out);
}

// Round 6
// 174.472 us; speedup vs baseline: 1.0479x; 1.0206x over previous
//
#include <hip/hip_runtime.h>
#include <stdint.h>

constexpr int B = 4;
constexpr int L = 2048;
constexpr int H = 8;
constexpr int D = 64;
constexpr int S = 40;    // sampled keys per query
constexpr int U = 40;    // top-k queries
constexpr int HD = H * D;          // 512
constexpr int NSEG = 8;            // top-k segments per (b,h)
constexpr int SEGL = L / NSEG;     // 256
constexpr int NC = 64;             // cumsum chunks
constexpr int CL = L / NC;         // 32
constexpr int ROCT = 8;            // row-octets per (b,h): 5 rows each
constexpr int RPO = U / ROCT;      // 5 rows per octet

constexpr int NBLK_SCORES = B * L / 4;     // 2048
constexpr int NBLK_CHUNK  = B * NC;        // 256
constexpr int NBLK_FLAG   = 64;            // zero 256 KB of flags, 4 KB/block

// monotone float->uint mapping: larger float => larger uint
__device__ __forceinline__ unsigned mono(float v) {
    unsigned u = __float_as_uint(v);
    return (u & 0x80000000u) ? ~u : (u | 0x80000000u);
}

typedef float f4v __attribute__((ext_vector_type(4)));

__device__ __forceinline__ float4 ntload4(const float4* p) {
    f4v v = __builtin_nontemporal_load((const f4v*)p);
    return make_float4(v.x, v.y, v.z, v.w);
}

// ---------------------------------------------------------------------------
// D1: fused sampled-scores + V-chunksum + flags-zero.
//  blocks [0,2048):  M[b,h,q] for all 8 heads, one wave per (b,q).
//    LANE-CONTIGUOUS K-row loads: lane l reads krow[l] and krow[64+l]
//    (16 cache lines per instruction instead of 32 with the old 32B-strided
//    pattern) -> halves L1 line-lookup cost of the 655 MB gather.
//    Lane l = 16g+m holds head g (qa/ka) and head g+4 (qb/kb), dim-quad m;
//    two dots reduced over the 16-lane group via 4 shfl_xor each.
//  blocks [2048,2304): per-chunk V totals (2 hd per thread)
//  blocks [2304,2368): zero flags (int4)
// ---------------------------------------------------------------------------
__global__ __launch_bounds__(256) void k_scores_chunks(
    const float4* __restrict__ Q4, const float4* __restrict__ K4,
    const int* __restrict__ idxs, const float* __restrict__ V,
    float* __restrict__ M, float* __restrict__ partial,
    int* __restrict__ flags)
{
    int i = blockIdx.x;

    if (i < NBLK_SCORES) {
        // ---------------- sampled scores ----------------
        int xcd = i & 7;
        int b = xcd >> 1;
        int qc = (i >> 3) * 2 + (xcd & 1);  // 0..511
        int w = threadIdx.x >> 6;
        int lane = threadIdx.x & 63;
        int q = qc * 4 + w;
        int g = lane >> 4;        // head pair: heads g and g+4
        int m = lane & 15;        // dim quad within head

        const float4* qrow = Q4 + (size_t)(b * L + q) * 128;
        float4 qa = ntload4(qrow + lane);        // head g,   dims 4m..4m+3
        float4 qb = ntload4(qrow + 64 + lane);   // head g+4, dims 4m..4m+3

        int v_idx = idxs[q * S + (lane < S ? lane : 0)];

        const float4* kbase = K4 + (size_t)b * L * 128;
        float mxA = -INFINITY, smA = 0.f;
        float mxB = -INFINITY, smB = 0.f;
        #pragma unroll 8
        for (int s = 0; s < S; ++s) {
            int ki = __shfl(v_idx, s);
            const float4* krow = kbase + (size_t)ki * 128;
            float4 ka = krow[lane];          // contiguous 1KB wave txn
            float4 kb = krow[64 + lane];     // contiguous 1KB wave txn
            float dA = qa.x * ka.x + qa.y * ka.y + qa.z * ka.z + qa.w * ka.w;
            float dB = qb.x * kb.x + qb.y * kb.y + qb.z * kb.z + qb.w * kb.w;
            dA += __shfl_xor(dA, 1);  dB += __shfl_xor(dB, 1);
            dA += __shfl_xor(dA, 2);  dB += __shfl_xor(dB, 2);
            dA += __shfl_xor(dA, 4);  dB += __shfl_xor(dB, 4);
            dA += __shfl_xor(dA, 8);  dB += __shfl_xor(dB, 8);
            mxA = fmaxf(mxA, dA);  smA += dA;
            mxB = fmaxf(mxB, dB);  smB += dB;
        }
        if (m == 0) {
            M[(b * 8 + g) * L + q]       = mxA - smA * (1.0f / (float)L);
            M[(b * 8 + g + 4) * L + q]   = mxB - smB * (1.0f / (float)L);
        }
    } else if (i < NBLK_SCORES + NBLK_CHUNK) {
        // ---------------- V chunk totals ----------------
        int cidx = i - NBLK_SCORES;
        int b = cidx >> 6, c = cidx & 63;
        int t = threadIdx.x;
        const float* vp = V + ((size_t)(b * L + c * CL)) * HD;
        float s0 = 0.f, s1 = 0.f;
        #pragma unroll
        for (int l = 0; l < CL; ++l) {
            s0 += __builtin_nontemporal_load(vp + (size_t)l * HD + t);
            s1 += __builtin_nontemporal_load(vp + (size_t)l * HD + t + 256);
        }
        partial[((size_t)b * NC + c) * HD + t]       = s0;
        partial[((size_t)b * NC + c) * HD + t + 256] = s1;
    } else {
        // ---------------- zero flags ----------------
        int fidx = i - (NBLK_SCORES + NBLK_CHUNK);   // 0..63
        ((int4*)flags)[fidx * 256 + threadIdx.x] = make_int4(0, 0, 0, 0);
    }
}

// ---------------------------------------------------------------------------
// D2: per-segment exact top-40 by rank counting. 256 one-wave blocks.
// ---------------------------------------------------------------------------
__global__ __launch_bounds__(64) void k_seg_topk(
    const float* __restrict__ M, unsigned long long* __restrict__ cand)
{
    int blk = blockIdx.x;           // bh*NSEG + seg
    int bh = blk >> 3, seg = blk & 7;
    int lane = threadIdx.x;
    int j0 = seg * SEGL + lane * 4;

    float4 v = *(const float4*)(M + (size_t)bh * L + j0);
    unsigned m[4] = { mono(v.x), mono(v.y), mono(v.z), mono(v.w) };
    int rank[4] = { 0, 0, 0, 0 };

    #pragma unroll 4
    for (int src = 0; src < 64; ++src) {
        #pragma unroll
        for (int slot = 0; slot < 4; ++slot) {
            unsigned bm = __shfl(m[slot], src);
            int bj = src * 4 + slot;
            #pragma unroll
            for (int s = 0; s < 4; ++s) {
                int myj = lane * 4 + s;
                rank[s] += (bm > m[s]) || (bm == m[s] && bj < myj);
            }
        }
    }

    unsigned long long* out = cand + (size_t)blk * U;
    #pragma unroll
    for (int s = 0; s < 4; ++s)
        if (rank[s] < U)
            out[rank[s]] = ((unsigned long long)m[s] << 32)
                         | (unsigned)(~(unsigned)(j0 + s));
}

// ---------------------------------------------------------------------------
// D3: attention spread 8x: one block per (b,h,row-octet). Each block
// redundantly recomputes the 320->40 merge, stages all 40 K/V rows + its 5
// Q rows, runs one row per wave (lane = key, in-register shfl softmax),
// writes its 5 upd rows. Only octet 0 writes flags.
// ---------------------------------------------------------------------------
__global__ __launch_bounds__(512) void k_attn(
    const unsigned long long* __restrict__ cand, const float4* __restrict__ Q4,
    const float4* __restrict__ K4, const float4* __restrict__ V4,
    int* __restrict__ flags, float* __restrict__ upd)
{
    __shared__ unsigned long long cnd[NSEG * U];       // 320 candidates
    __shared__ int top_idx[U];
    __shared__ __align__(16) float Qs[RPO * 68];       // 5 rows, pad 68
    __shared__ __align__(16) float Kst[64 * 65];       // TRANSPOSED: [d*65+k]
    __shared__ __align__(16) float Vs[U * 68];         // row-major, pad 68
    __shared__ __align__(16) float Plds[RPO * 44];     // zero-padded rows

    int blk = blockIdx.x;
    int bh = blk >> 3, oct = blk & 7;
    int b = bh >> 3, h = bh & 7;
    int tid = threadIdx.x;
    int wv = tid >> 6, lane = tid & 63;

    for (int t = tid; t < NSEG * U; t += 512)
        cnd[t] = cand[(size_t)bh * NSEG * U + t];
    __syncthreads();

    // ---- merge: top-40 of 320, one candidate/thread, unrolled LDS scan ----
    if (tid < NSEG * U) {
        unsigned long long ka = cnd[tid];
        int ra = 0;
        #pragma unroll 8
        for (int j = 0; j < NSEG * U; ++j) ra += (cnd[j] > ka);
        if (ra < U) top_idx[ra] = (int)(~(unsigned)ka);
    }
    __syncthreads();

    if (oct == 0 && tid < U) flags[bh * L + top_idx[tid]] = tid + 1;

    // ---- stage K rows 0..39 (transposed), V rows 0..39, 5 Q rows ----------
    for (int i = tid; i < U * 16; i += 512) {
        int r = i >> 4, d4 = i & 15;
        size_t kvbase = ((size_t)(b * L + r) * H + h) * 16 + d4;
        float4 kv = K4[kvbase];
        Kst[(4 * d4 + 0) * 65 + r] = kv.x;
        Kst[(4 * d4 + 1) * 65 + r] = kv.y;
        Kst[(4 * d4 + 2) * 65 + r] = kv.z;
        Kst[(4 * d4 + 3) * 65 + r] = kv.w;
        *(float4*)(Vs + r * 68 + d4 * 4) = V4[kvbase];
    }
    if (tid < RPO * 16) {
        int rl = tid >> 4, d4 = tid & 15;
        int qg = top_idx[oct * RPO + rl];
        *(float4*)(Qs + rl * 68 + d4 * 4) =
            Q4[((size_t)(b * L + qg) * H + h) * 16 + d4];
    }
    __syncthreads();

    // ---- scores + in-register softmax: wave wv<5 owns global row ----------
    const float scale = 0.125f;   // 1/sqrt(64)
    if (wv < RPO) {
        int rg = oct * RPO + wv;   // global rank row
        int k = lane;
        float acc = 0.f;
        #pragma unroll
        for (int d0 = 0; d0 < D; d0 += 4) {
            float4 qv = *(const float4*)(Qs + wv * 68 + d0);   // broadcast
            acc += qv.x * Kst[(d0 + 0) * 65 + k];
            acc += qv.y * Kst[(d0 + 1) * 65 + k];
            acc += qv.z * Kst[(d0 + 2) * 65 + k];
            acc += qv.w * Kst[(d0 + 3) * 65 + k];
        }
        // causal over rank: keys k<=rg only
        float sc = (k <= rg) ? acc * scale : -INFINITY;
        float mx = sc;
        #pragma unroll
        for (int off = 32; off >= 1; off >>= 1)
            mx = fmaxf(mx, __shfl_xor(mx, off));
        float e = __expf(sc - mx);            // masked lanes -> 0
        float sum = e;
        #pragma unroll
        for (int off = 32; off >= 1; off >>= 1)
            sum += __shfl_xor(sum, off);
        float p = e / sum;
        if (k < U) Plds[wv * 44 + k] = p;     // zeros where masked
    }
    __syncthreads();

    // ---- PV: 5 rows x 64 dims, fixed-40 fully unrolled --------------------
    if (tid < RPO * D) {
        int rl = tid >> 6, d = tid & 63;
        float acc = 0.f;
        #pragma unroll
        for (int kk = 0; kk < U; kk += 4) {
            float4 pv = *(const float4*)(Plds + rl * 44 + kk);  // broadcast
            acc += pv.x * Vs[(kk + 0) * 68 + d];
            acc += pv.y * Vs[(kk + 1) * 68 + d];
            acc += pv.z * Vs[(kk + 2) * 68 + d];
            acc += pv.w * Vs[(kk + 3) * 68 + d];
        }
        upd[((size_t)bh * U + oct * RPO + rl) * D + d] = acc;
    }
}

// ---------------------------------------------------------------------------
// D4: emit. Each block (b,c) computes its exclusive prefix by summing the
// c predecessor chunk totals with 4 independent accumulators (breaks the
// serial L2-latency chain), then emits cumsum with flagged rows replaced.
// ---------------------------------------------------------------------------
__global__ __launch_bounds__(512) void k_out(
    const float* __restrict__ V, const float* __restrict__ partial,
    const int* __restrict__ flags, const float* __restrict__ upd,
    float* __restrict__ out)
{
    int b = blockIdx.x >> 6;
    int c = blockIdx.x & 63;
    int hd = threadIdx.x;
    int h = hd >> 6, d = hd & 63;

    // exclusive prefix over predecessor chunk totals, 4-way ILP
    const float* pp = partial + (size_t)b * NC * HD + hd;
    float a0 = 0.f, a1 = 0.f, a2 = 0.f, a3 = 0.f;
    int j = 0;
    for (; j + 4 <= c; j += 4) {
        a0 += pp[(size_t)(j + 0) * HD];
        a1 += pp[(size_t)(j + 1) * HD];
        a2 += pp[(size_t)(j + 2) * HD];
        a3 += pp[(size_t)(j + 3) * HD];
    }
    for (; j < c; ++j) a0 += pp[(size_t)j * HD];
    float acc = (a0 + a1) + (a2 + a3);

    const float* vp = V + ((size_t)(b * L + c * CL)) * HD + hd;
    float*       op = out + ((size_t)(b * L + c * CL)) * HD + hd;
    const int*   fp = flags + (b * H + h) * L + c * CL;
    const float* up = upd + (size_t)(b * H + h) * U * D + d;

    #pragma unroll 4
    for (int l = 0; l < CL; ++l) {
        acc += vp[(size_t)l * HD];
        int f = fp[l];
        float o = f ? up[(size_t)(f - 1) * D] : acc;
        __builtin_nontemporal_store(o, op + (size_t)l * HD);
    }
}

extern "C" void kernel_launch(void* const* d_in, const int* in_sizes, int n_in,
                              void* d_out, int out_size, void* d_ws, size_t ws_size,
                              hipStream_t stream)
{
    const float* Q   = (const float*)d_in[0];
    const float* K   = (const float*)d_in[1];
    const float* V   = (const float*)d_in[2];
    const int*  idxs = (const int*)d_in[3];
    float* out = (float*)d_out;

    char* ws = (char*)d_ws;
    float* M        = (float*)(ws);                 // B*H*L          = 256 KB
    int*   flags    = (int*)  (ws + 262144);        // B*H*L          = 256 KB
    float* upd      = (float*)(ws + 524288);        // B*H*U*D        = 320 KB
    float* partial  = (float*)(ws + 851968);        // B*NC*HD        = 512 KB
    unsigned long long* cand = (unsigned long long*)(ws + 1376256);  // 80 KB

    k_scores_chunks<<<NBLK_SCORES + NBLK_CHUNK + NBLK_FLAG, 256, 0, stream>>>(
        (const float4*)Q, (const float4*)K, idxs, V, M, partial, flags);
    k_seg_topk <<<B * H * NSEG, 64, 0, stream>>>(M, cand);
    k_attn     <<<B * H * ROCT, 512, 0, stream>>>(cand, (const float4*)Q, (const float4*)K,
                                                  (const float4*)V, flags, upd);
    k_out      <<<B * NC,      512, 0, stream>>>(V, partial, flags, upd, out);
}